// Round 2
// baseline (69.322 us; speedup 1.0000x reference)
//
#include <hip/hip_runtime.h>

#define NUM_BINS 256
#define IMG_W 1024
#define IMG_H 1024

// One block (256 threads) per 128x128 tile. 2048 tiles.
__global__ __launch_bounds__(256, 8) void clahe_kernel(const float* __restrict__ img,
                                                       float* __restrict__ out) {
    const int tile = blockIdx.x;          // 0..2047
    const int b  = tile >> 6;
    const int ty = (tile >> 3) & 7;
    const int tx = tile & 7;

    const size_t base = ((size_t)b * IMG_H + (size_t)ty * 128) * IMG_W + (size_t)tx * 128;
    const float* __restrict__ src = img + base;
    float* __restrict__ dst = out + base;

    const int t = threadIdx.x;            // 0..255
    const int w = t >> 6;                 // wave id
    const int c2 = (t >> 1) & 15;         // column-pair for packed histogram
    const unsigned int hinc = 1u << ((t & 1) << 4);  // lo/hi u16 half

    // hist[bin][c2]: word packs two u16 counts. bank = (bin&1)*16 + c2 ->
    // distinct lane-pairs never share a bank during atomics.
    __shared__ unsigned int hist[NUM_BINS * 16];  // 16 KB
    __shared__ float cdf[NUM_BINS];
    __shared__ float exw[4];
    __shared__ float wsum[4];

    #pragma unroll
    for (int j = 0; j < 16; ++j) hist[t + (j << 8)] = 0u;
    __syncthreads();

    // thread's element f = t + i*256 -> row = f>>5, col4 = f&31; i step = +8 rows
    const float* pbase = src + (size_t)(t >> 5) * IMG_W + ((t & 31) << 2);
    float*       dbase = dst + (size_t)(t >> 5) * IMG_W + ((t & 31) << 2);

    // ---- Pass 1: histogram with register double-buffer (4 float4 in flight)
    float4 va[4], vb[4];
    #pragma unroll
    for (int j = 0; j < 4; ++j)
        va[j] = *reinterpret_cast<const float4*>(pbase + (size_t)j * 8 * IMG_W);

    #pragma unroll
    for (int g = 0; g < 4; ++g) {
        if (g < 3) {
            #pragma unroll
            for (int j = 0; j < 4; ++j)
                vb[j] = *reinterpret_cast<const float4*>(pbase + (size_t)((g + 1) * 4 + j) * 8 * IMG_W);
        }
        #pragma unroll
        for (int j = 0; j < 4; ++j) {
            const float4 v = va[j];
            atomicAdd(&hist[(min(255, (int)(v.x * 256.0f)) << 4) + c2], hinc);
            atomicAdd(&hist[(min(255, (int)(v.y * 256.0f)) << 4) + c2], hinc);
            atomicAdd(&hist[(min(255, (int)(v.z * 256.0f)) << 4) + c2], hinc);
            atomicAdd(&hist[(min(255, (int)(v.w * 256.0f)) << 4) + c2], hinc);
        }
        if (g < 3) {
            #pragma unroll
            for (int j = 0; j < 4; ++j) va[j] = vb[j];
        }
    }
    __syncthreads();

    // ---- Column-sum bin t (rotated read: 2 lanes/bank = free)
    unsigned int hsum = 0;
    const int rowbase = t << 4;
    #pragma unroll
    for (int j = 0; j < 16; ++j) {
        const unsigned int x = hist[rowbase + ((j + (t >> 1)) & 15)];
        hsum += (x & 0xFFFFu) + (x >> 16);
    }
    const int h = (int)hsum;

    // ---- Excess reduction (wave shfl_xor) runs concurrently with the scan below.
    float ex = (float)max(h - 128, 0);
    #pragma unroll
    for (int off = 32; off > 0; off >>= 1) ex += __shfl_xor(ex, off);
    if ((t & 63) == 0) exw[w] = ex;

    // ---- Wave-level inclusive scan of min(h,128); excess/256 is a uniform
    // additive term, folded in analytically after the barrier.
    const float minh = fminf((float)h, 128.0f);
    float x = minh;
    #pragma unroll
    for (int off = 1; off < 64; off <<= 1) {
        const float y = __shfl_up(x, off);
        if ((t & 63) >= off) x += y;
    }
    if ((t & 63) == 63) wsum[w] = x;
    __syncthreads();

    const float excess = exw[0] + exw[1] + exw[2] + exw[3];
    float prefix = 0.0f;
    if (w > 0) prefix += wsum[0];
    if (w > 1) prefix += wsum[1];
    if (w > 2) prefix += wsum[2];
    const float summinh = wsum[0] + wsum[1] + wsum[2] + wsum[3];
    const float e256 = excess * (1.0f / 256.0f);
    const float total = summinh + excess;
    cdf[t] = (x + prefix + (float)(t + 1) * e256) / total;
    __syncthreads();

    // ---- Pass 2: map + write, double-buffered (re-read is L2/L3-resident)
    #pragma unroll
    for (int j = 0; j < 4; ++j)
        va[j] = *reinterpret_cast<const float4*>(pbase + (size_t)j * 8 * IMG_W);

    #pragma unroll
    for (int g = 0; g < 4; ++g) {
        if (g < 3) {
            #pragma unroll
            for (int j = 0; j < 4; ++j)
                vb[j] = *reinterpret_cast<const float4*>(pbase + (size_t)((g + 1) * 4 + j) * 8 * IMG_W);
        }
        #pragma unroll
        for (int j = 0; j < 4; ++j) {
            const float4 v = va[j];
            float4 o;
            o.x = cdf[min(255, (int)(v.x * 255.0f))];
            o.y = cdf[min(255, (int)(v.y * 255.0f))];
            o.z = cdf[min(255, (int)(v.z * 255.0f))];
            o.w = cdf[min(255, (int)(v.w * 255.0f))];
            *reinterpret_cast<float4*>(dbase + (size_t)(g * 4 + j) * 8 * IMG_W) = o;
        }
        if (g < 3) {
            #pragma unroll
            for (int j = 0; j < 4; ++j) va[j] = vb[j];
        }
    }
}

extern "C" void kernel_launch(void* const* d_in, const int* in_sizes, int n_in,
                              void* d_out, int out_size, void* d_ws, size_t ws_size,
                              hipStream_t stream) {
    const float* img = (const float*)d_in[0];
    float* out = (float*)d_out;
    clahe_kernel<<<2048, 256, 0, stream>>>(img, out);
}

// Round 3
// 65.584 us; speedup vs baseline: 1.0570x; 1.0570x over previous
//
#include <hip/hip_runtime.h>

#define NUM_BINS 256
#define IMG_W 1024
#define IMG_H 1024

typedef float f32x4 __attribute__((ext_vector_type(4)));

// One block (256 threads) per 128x128 tile. 2048 tiles.
__global__ __launch_bounds__(256, 8) void clahe_kernel(const float* __restrict__ img,
                                                       float* __restrict__ out) {
    const int tile = blockIdx.x;          // 0..2047
    const int b  = tile >> 6;
    const int ty = (tile >> 3) & 7;
    const int tx = tile & 7;

    const size_t base = ((size_t)b * IMG_H + (size_t)ty * 128) * IMG_W + (size_t)tx * 128;
    const float* __restrict__ src = img + base;
    float* __restrict__ dst = out + base;

    const int t = threadIdx.x;            // 0..255
    const int w = t >> 6;                 // wave id

    __shared__ int   hist[4][NUM_BINS];   // 4 KB
    __shared__ float cdf[NUM_BINS];
    __shared__ float exw[4];
    __shared__ float wsum[4];

    hist[0][t] = 0; hist[1][t] = 0; hist[2][t] = 0; hist[3][t] = 0;
    __syncthreads();

    // thread's element f = t + i*256 -> row = (t>>5) + 8*i, col = (t&31)*4
    const float* pbase = src + (size_t)(t >> 5) * IMG_W + ((t & 31) << 2);
    float*       dbase = dst + (size_t)(t >> 5) * IMG_W + ((t & 31) << 2);

    // ---- Pass 1: histogram + stash packed 255-indices in registers.
    // Rolling 2-group (4 float4 each) prefetch.
    f32x4 va[4], vb[4];
    unsigned int pk[16];
    #pragma unroll
    for (int j = 0; j < 4; ++j)
        va[j] = __builtin_nontemporal_load(
            reinterpret_cast<const f32x4*>(pbase + (size_t)j * 8 * IMG_W));

    #pragma unroll
    for (int g = 0; g < 4; ++g) {
        if (g < 3) {
            #pragma unroll
            for (int j = 0; j < 4; ++j)
                vb[j] = __builtin_nontemporal_load(
                    reinterpret_cast<const f32x4*>(pbase + (size_t)((g + 1) * 4 + j) * 8 * IMG_W));
        }
        #pragma unroll
        for (int j = 0; j < 4; ++j) {
            const f32x4 v = va[j];
            const int h0 = min(255, (int)(v.x * 256.0f));
            const int h1 = min(255, (int)(v.y * 256.0f));
            const int h2 = min(255, (int)(v.z * 256.0f));
            const int h3 = min(255, (int)(v.w * 256.0f));
            atomicAdd(&hist[w][h0], 1);
            atomicAdd(&hist[w][h1], 1);
            atomicAdd(&hist[w][h2], 1);
            atomicAdd(&hist[w][h3], 1);
            const unsigned int m0 = (unsigned int)min(255, (int)(v.x * 255.0f));
            const unsigned int m1 = (unsigned int)min(255, (int)(v.y * 255.0f));
            const unsigned int m2 = (unsigned int)min(255, (int)(v.z * 255.0f));
            const unsigned int m3 = (unsigned int)min(255, (int)(v.w * 255.0f));
            pk[g * 4 + j] = m0 | (m1 << 8) | (m2 << 16) | (m3 << 24);
        }
        if (g < 3) {
            #pragma unroll
            for (int j = 0; j < 4; ++j) va[j] = vb[j];
        }
    }
    __syncthreads();

    // ---- Per-bin total (bank-conflict-free: bank = t%32, 2 lanes/bank = free)
    const int h = hist[0][t] + hist[1][t] + hist[2][t] + hist[3][t];

    // ---- Excess reduction (wave shfl) + wave-level inclusive scan of min(h,128).
    // excess/256 is a uniform additive term folded in analytically.
    float ex = (float)max(h - 128, 0);
    #pragma unroll
    for (int off = 32; off > 0; off >>= 1) ex += __shfl_xor(ex, off);
    if ((t & 63) == 0) exw[w] = ex;

    const float minh = fminf((float)h, 128.0f);
    float x = minh;
    #pragma unroll
    for (int off = 1; off < 64; off <<= 1) {
        const float y = __shfl_up(x, off);
        if ((t & 63) >= off) x += y;
    }
    if ((t & 63) == 63) wsum[w] = x;
    __syncthreads();

    const float excess = exw[0] + exw[1] + exw[2] + exw[3];
    float prefix = 0.0f;
    if (w > 0) prefix += wsum[0];
    if (w > 1) prefix += wsum[1];
    if (w > 2) prefix += wsum[2];
    const float summinh = wsum[0] + wsum[1] + wsum[2] + wsum[3];
    const float e256 = excess * (1.0f / 256.0f);
    const float total = summinh + excess;
    cdf[t] = (x + prefix + (float)(t + 1) * e256) / total;
    __syncthreads();

    // ---- Pass 2: pure register-unpack -> LDS gather -> streaming store.
    #pragma unroll
    for (int i = 0; i < 16; ++i) {
        const unsigned int u = pk[i];
        f32x4 o;
        o.x = cdf[u & 255u];
        o.y = cdf[(u >> 8) & 255u];
        o.z = cdf[(u >> 16) & 255u];
        o.w = cdf[u >> 24];
        __builtin_nontemporal_store(
            o, reinterpret_cast<f32x4*>(dbase + (size_t)i * 8 * IMG_W));
    }
}

extern "C" void kernel_launch(void* const* d_in, const int* in_sizes, int n_in,
                              void* d_out, int out_size, void* d_ws, size_t ws_size,
                              hipStream_t stream) {
    const float* img = (const float*)d_in[0];
    float* out = (float*)d_out;
    clahe_kernel<<<2048, 256, 0, stream>>>(img, out);
}

// Round 4
// 46.597 us; speedup vs baseline: 1.4877x; 1.4075x over previous
//
#include <hip/hip_runtime.h>

#define IMG_W 1024
#define IMG_H 1024

typedef float f32x4 __attribute__((ext_vector_type(4)));

// One block (256 threads) per PAIR of horizontally-adjacent 128x128 tiles.
// 1024 blocks = 4 blocks/CU: software-pipelined so store(A) overlaps read(B).
__global__ __launch_bounds__(256) void clahe_kernel(const float* __restrict__ img,
                                                    float* __restrict__ out) {
    const int pair = blockIdx.x;          // 0..1023
    const int tA = pair << 1;             // even tile index
    const int b  = tA >> 6;
    const int ty = (tA >> 3) & 7;
    const int tx = tA & 7;                // even

    const size_t baseA = ((size_t)b * IMG_H + (size_t)ty * 128) * IMG_W + (size_t)tx * 128;
    const size_t baseB = baseA + 128;     // adjacent tile, same rows

    const int t = threadIdx.x;            // 0..255
    const int w = t >> 6;                 // wave id

    __shared__ int   hist[4][256];        // 4 KB
    __shared__ float cdf[2][256];         // 2 KB (A=0, B=1)
    __shared__ float exw[4];
    __shared__ float wsum[4];

    const size_t toff = (size_t)(t >> 5) * IMG_W + ((t & 31) << 2);
    const float* __restrict__ pA = img + baseA + toff;
    const float* __restrict__ pB = img + baseB + toff;
    float* __restrict__ dA = out + baseA + toff;
    float* __restrict__ dB = out + baseB + toff;

    hist[0][t] = 0; hist[1][t] = 0; hist[2][t] = 0; hist[3][t] = 0;
    __syncthreads();

    unsigned int pkA[16], pkB[16];

    // clip+scan: reads hist, zeroes it, publishes cdf[s]. One internal barrier;
    // caller must barrier after before consuming cdf[s].
    auto scan_fn = [&](int s) {
        const int h = hist[0][t] + hist[1][t] + hist[2][t] + hist[3][t];
        hist[0][t] = 0; hist[1][t] = 0; hist[2][t] = 0; hist[3][t] = 0;

        float ex = (float)max(h - 128, 0);
        #pragma unroll
        for (int off = 32; off > 0; off >>= 1) ex += __shfl_xor(ex, off);
        if ((t & 63) == 0) exw[w] = ex;

        float x = fminf((float)h, 128.0f);
        #pragma unroll
        for (int off = 1; off < 64; off <<= 1) {
            const float y = __shfl_up(x, off);
            if ((t & 63) >= off) x += y;
        }
        if ((t & 63) == 63) wsum[w] = x;
        __syncthreads();

        const float excess = exw[0] + exw[1] + exw[2] + exw[3];
        float prefix = 0.0f;
        if (w > 0) prefix += wsum[0];
        if (w > 1) prefix += wsum[1];
        if (w > 2) prefix += wsum[2];
        const float summinh = wsum[0] + wsum[1] + wsum[2] + wsum[3];
        const float e256 = excess * (1.0f / 256.0f);
        const float total = summinh + excess;
        cdf[s][t] = (x + prefix + (float)(t + 1) * e256) / total;
    };

    // ---- Phase 1: read A + hist A (rolling prefetch), stash pkA
    {
        f32x4 va[4], vb[4];
        #pragma unroll
        for (int j = 0; j < 4; ++j)
            va[j] = *reinterpret_cast<const f32x4*>(pA + (size_t)j * 8 * IMG_W);
        #pragma unroll
        for (int g = 0; g < 4; ++g) {
            if (g < 3) {
                #pragma unroll
                for (int j = 0; j < 4; ++j)
                    vb[j] = *reinterpret_cast<const f32x4*>(pA + (size_t)((g + 1) * 4 + j) * 8 * IMG_W);
            }
            #pragma unroll
            for (int j = 0; j < 4; ++j) {
                const f32x4 v = va[j];
                atomicAdd(&hist[w][min(255, (int)(v.x * 256.0f))], 1);
                atomicAdd(&hist[w][min(255, (int)(v.y * 256.0f))], 1);
                atomicAdd(&hist[w][min(255, (int)(v.z * 256.0f))], 1);
                atomicAdd(&hist[w][min(255, (int)(v.w * 256.0f))], 1);
                pkA[g * 4 + j] = (unsigned int)min(255, (int)(v.x * 255.0f))
                               | ((unsigned int)min(255, (int)(v.y * 255.0f)) << 8)
                               | ((unsigned int)min(255, (int)(v.z * 255.0f)) << 16)
                               | ((unsigned int)min(255, (int)(v.w * 255.0f)) << 24);
            }
            if (g < 3) {
                #pragma unroll
                for (int j = 0; j < 4; ++j) va[j] = vb[j];
            }
        }
    }
    __syncthreads();

    // ---- Phase 2: scan A -> cdf[0] (also zeroes hist for B)
    scan_fn(0);
    __syncthreads();

    // ---- Phase 3: store mapped-A interleaved with read B + hist B
    {
        f32x4 va[4], vb[4];
        #pragma unroll
        for (int j = 0; j < 4; ++j)
            va[j] = *reinterpret_cast<const f32x4*>(pB + (size_t)j * 8 * IMG_W);
        #pragma unroll
        for (int g = 0; g < 4; ++g) {
            if (g < 3) {
                #pragma unroll
                for (int j = 0; j < 4; ++j)
                    vb[j] = *reinterpret_cast<const f32x4*>(pB + (size_t)((g + 1) * 4 + j) * 8 * IMG_W);
            }
            // store A group g (LDS gather + NT store)
            #pragma unroll
            for (int j = 0; j < 4; ++j) {
                const unsigned int u = pkA[g * 4 + j];
                f32x4 o;
                o.x = cdf[0][u & 255u];
                o.y = cdf[0][(u >> 8) & 255u];
                o.z = cdf[0][(u >> 16) & 255u];
                o.w = cdf[0][u >> 24];
                __builtin_nontemporal_store(
                    o, reinterpret_cast<f32x4*>(dA + (size_t)(g * 4 + j) * 8 * IMG_W));
            }
            // hist B group g
            #pragma unroll
            for (int j = 0; j < 4; ++j) {
                const f32x4 v = va[j];
                atomicAdd(&hist[w][min(255, (int)(v.x * 256.0f))], 1);
                atomicAdd(&hist[w][min(255, (int)(v.y * 256.0f))], 1);
                atomicAdd(&hist[w][min(255, (int)(v.z * 256.0f))], 1);
                atomicAdd(&hist[w][min(255, (int)(v.w * 256.0f))], 1);
                pkB[g * 4 + j] = (unsigned int)min(255, (int)(v.x * 255.0f))
                               | ((unsigned int)min(255, (int)(v.y * 255.0f)) << 8)
                               | ((unsigned int)min(255, (int)(v.z * 255.0f)) << 16)
                               | ((unsigned int)min(255, (int)(v.w * 255.0f)) << 24);
            }
            if (g < 3) {
                #pragma unroll
                for (int j = 0; j < 4; ++j) va[j] = vb[j];
            }
        }
    }
    __syncthreads();

    // ---- Phase 4: scan B -> cdf[1]
    scan_fn(1);
    __syncthreads();

    // ---- Phase 5: store mapped-B
    #pragma unroll
    for (int i = 0; i < 16; ++i) {
        const unsigned int u = pkB[i];
        f32x4 o;
        o.x = cdf[1][u & 255u];
        o.y = cdf[1][(u >> 8) & 255u];
        o.z = cdf[1][(u >> 16) & 255u];
        o.w = cdf[1][u >> 24];
        __builtin_nontemporal_store(
            o, reinterpret_cast<f32x4*>(dB + (size_t)i * 8 * IMG_W));
    }
}

extern "C" void kernel_launch(void* const* d_in, const int* in_sizes, int n_in,
                              void* d_out, int out_size, void* d_ws, size_t ws_size,
                              hipStream_t stream) {
    const float* img = (const float*)d_in[0];
    float* out = (float*)d_out;
    clahe_kernel<<<1024, 256, 0, stream>>>(img, out);
}